// Round 2
// baseline (309.397 us; speedup 1.0000x reference)
//
#include <hip/hip_runtime.h>
#include <math.h>

#ifndef M_PI
#define M_PI 3.14159265358979323846
#endif

#define SEQ 4096
#define DIM 512

// per-stream LDS region: exchange1 needs <=568 slots, exchange2 <=652; pad to 656
#define REG_SZ 656

// ---------- wave-local LDS sync ----------
// All LDS exchanges are intra-wave (each wave owns private regions). A wave64
// executes in lockstep, so write->read exchange only needs the DS queue
// drained (lgkmcnt(0)) -- not s_barrier, and no vmcnt drain.
__device__ __forceinline__ void wsync(){
  asm volatile("s_waitcnt lgkmcnt(0)" ::: "memory");
  __builtin_amdgcn_wave_barrier();
}

// ---------- complex helpers (float2 = {re, im}) ----------
__device__ __forceinline__ float2 cadd(float2 a, float2 b){ return make_float2(a.x+b.x, a.y+b.y); }
__device__ __forceinline__ float2 csub(float2 a, float2 b){ return make_float2(a.x-b.x, a.y-b.y); }
__device__ __forceinline__ float2 cmul(float2 a, float2 b){
  return make_float2(fmaf(a.x, b.x, -(a.y*b.y)), fmaf(a.x, b.y, a.y*b.x));
}
__device__ __forceinline__ float2 cmulc(float2 a, float2 b){ // a * conj(b)
  return make_float2(fmaf(a.x, b.x, a.y*b.y), fmaf(a.y, b.x, -(a.x*b.y)));
}
__device__ __forceinline__ float2 mul_mi(float2 a){ return make_float2(a.y, -a.x); } // a * (-i)

// 8-point DFT, natural in / natural out, W = exp(-2*pi*i/8)
__device__ __forceinline__ void dft8(const float2* in, float2* out){
  float2 t0 = cadd(in[0], in[4]), t1 = csub(in[0], in[4]);
  float2 t2 = cadd(in[2], in[6]), t3 = csub(in[2], in[6]);
  float2 E0 = cadd(t0, t2), E2 = csub(t0, t2);
  float2 m3 = mul_mi(t3);
  float2 E1 = cadd(t1, m3), E3 = csub(t1, m3);
  float2 s0 = cadd(in[1], in[5]), s1 = csub(in[1], in[5]);
  float2 s2 = cadd(in[3], in[7]), s3 = csub(in[3], in[7]);
  float2 O0 = cadd(s0, s2), O2 = csub(s0, s2);
  float2 n3 = mul_mi(s3);
  float2 O1 = cadd(s1, n3), O3 = csub(s1, n3);
  const float C = 0.70710678118654752440f;
  float2 w1o = make_float2(C*(O1.x + O1.y), C*(O1.y - O1.x));   // W8^1 * O1
  float2 w2o = mul_mi(O2);                                       // W8^2 * O2
  float2 w3o = make_float2(C*(O3.y - O3.x), -(C*(O3.x + O3.y))); // W8^3 * O3
  out[0] = cadd(E0, O0); out[4] = csub(E0, O0);
  out[1] = cadd(E1, w1o); out[5] = csub(E1, w1o);
  out[2] = cadd(E2, w2o); out[6] = csub(E2, w2o);
  out[3] = cadd(E3, w3o); out[7] = csub(E3, w3o);
}

// unscaled inverse 8-pt DFT: IDFT(a)[k] == DFT(a)[(-k) mod 8]
__device__ __forceinline__ void idft8(const float2* in, float2* out){
  float2 t[8];
  dft8(in, t);
  out[0]=t[0]; out[1]=t[7]; out[2]=t[6]; out[3]=t[5];
  out[4]=t[4]; out[5]=t[3]; out[6]=t[2]; out[7]=t[1];
}

// Twiddles via recurrence: 2 sincosf + 14 cmul (instead of 14 sincosf).
// Unit-magnitude drift over 7 steps is ~few ulp, far inside tolerance.
__device__ __forceinline__ void make_twiddles(int lane, float2* wA, float2* wB){
  const int b = lane & 7;
  float sv, cv;
  sincosf(-2.0f*(float)M_PI*(float)lane*(1.0f/512.0f), &sv, &cv);
  const float2 a1 = make_float2(cv, sv);
  sincosf(-2.0f*(float)M_PI*(float)b*(1.0f/64.0f), &sv, &cv);
  const float2 b1 = make_float2(cv, sv);
  wA[0] = make_float2(1.f, 0.f); wB[0] = make_float2(1.f, 0.f);
  wA[1] = a1; wB[1] = b1;
  #pragma unroll
  for (int r = 2; r < 8; ++r){ wA[r] = cmul(wA[r-1], a1); wB[r] = cmul(wB[r-1], b1); }
}

// ---------- 512-pt FFT, one wave (64 lanes x 8 complex regs) ----------
// Exchange addressing (bank-pair = (idx mod 16) must be bijective over each
// aligned 16-lane phase for conflict-free 8B LDS access):
//   exchange1: write idx = 72*r + lane        -> pair (8r+lane)%16  bijective
//              read  idx = 72*a + b + 8*j2    -> pair (8a+b)%16     bijective
//   exchange2: f2(a,u,w) = a + 82*u + 10*w    (bijective: a+10w<=77<82)
//              write (u const): pair (a+10w)%16  -> {0,10,4,14,8,2,12,6}+bit  OK
//              read  (w const): pair (a+2u)%16   -> bijective                 OK

// single-stream forward (used by the p-spectrum kernel / fallback)
__device__ __forceinline__ void fft512_fwd(float2* v, float2* lds, int lane,
                                           const float2* wA, const float2* wB){
  const int a = lane >> 3, b = lane & 7;
  float2 t[8];
  dft8(v, t);
  #pragma unroll
  for (int r = 1; r < 8; ++r) t[r] = cmul(t[r], wA[r]);
  wsync();
  #pragma unroll
  for (int r = 0; r < 8; ++r) lds[72*r + lane] = t[r];
  wsync();
  #pragma unroll
  for (int j2 = 0; j2 < 8; ++j2) v[j2] = lds[72*a + b + 8*j2];
  dft8(v, t);
  #pragma unroll
  for (int r2 = 1; r2 < 8; ++r2) t[r2] = cmul(t[r2], wB[r2]);
  wsync();
  #pragma unroll
  for (int r2 = 0; r2 < 8; ++r2) lds[a + 82*r2 + 10*b] = t[r2];
  wsync();
  #pragma unroll
  for (int i2 = 0; i2 < 8; ++i2) v[i2] = lds[a + 82*b + 10*i2];
  dft8(v, t);
  #pragma unroll
  for (int m = 0; m < 8; ++m) v[m] = t[m];
}

// ---------- two-stream interleaved forward / inverse ----------
// Streams A,B are independent FFTs in separate LDS regions; interleaving
// them doubles the independent VALU work adjacent to every DS round-trip,
// so the compiler's fine-grained lgkmcnt scheduling can overlap stream B's
// butterflies with stream A's LDS latency (and vice versa).
__device__ __forceinline__ void fft512_fwd2(float2* vA, float2* vB,
                                            float2* ldsA, float2* ldsB, int lane,
                                            const float2* wA, const float2* wB){
  const int a = lane >> 3, b = lane & 7;
  float2 tA[8], tB[8];
  dft8(vA, tA); dft8(vB, tB);
  #pragma unroll
  for (int r = 1; r < 8; ++r){ tA[r] = cmul(tA[r], wA[r]); tB[r] = cmul(tB[r], wA[r]); }
  wsync();
  #pragma unroll
  for (int r = 0; r < 8; ++r){ ldsA[72*r + lane] = tA[r]; ldsB[72*r + lane] = tB[r]; }
  wsync();
  #pragma unroll
  for (int j2 = 0; j2 < 8; ++j2){ vA[j2] = ldsA[72*a + b + 8*j2]; vB[j2] = ldsB[72*a + b + 8*j2]; }
  dft8(vA, tA); dft8(vB, tB);
  #pragma unroll
  for (int r2 = 1; r2 < 8; ++r2){ tA[r2] = cmul(tA[r2], wB[r2]); tB[r2] = cmul(tB[r2], wB[r2]); }
  wsync();
  #pragma unroll
  for (int r2 = 0; r2 < 8; ++r2){ ldsA[a + 82*r2 + 10*b] = tA[r2]; ldsB[a + 82*r2 + 10*b] = tB[r2]; }
  wsync();
  #pragma unroll
  for (int i2 = 0; i2 < 8; ++i2){ vA[i2] = ldsA[a + 82*b + 10*i2]; vB[i2] = ldsB[a + 82*b + 10*i2]; }
  dft8(vA, tA); dft8(vB, tB);
  #pragma unroll
  for (int m = 0; m < 8; ++m){ vA[m] = tA[m]; vB[m] = tB[m]; }
}

__device__ __forceinline__ void fft512_inv2(float2* vA, float2* vB,
                                            float2* ldsA, float2* ldsB, int lane,
                                            const float2* wA, const float2* wB){
  const int a = lane >> 3, b = lane & 7;
  float2 tA[8], tB[8];
  idft8(vA, tA); idft8(vB, tB);
  wsync();
  #pragma unroll
  for (int i2 = 0; i2 < 8; ++i2){ ldsA[a + 82*b + 10*i2] = tA[i2]; ldsB[a + 82*b + 10*i2] = tB[i2]; }
  wsync();
  #pragma unroll
  for (int r2 = 0; r2 < 8; ++r2){ vA[r2] = ldsA[a + 82*r2 + 10*b]; vB[r2] = ldsB[a + 82*r2 + 10*b]; }
  #pragma unroll
  for (int r2 = 1; r2 < 8; ++r2){ vA[r2] = cmulc(vA[r2], wB[r2]); vB[r2] = cmulc(vB[r2], wB[r2]); }
  idft8(vA, tA); idft8(vB, tB);
  wsync();
  #pragma unroll
  for (int j2 = 0; j2 < 8; ++j2){ ldsA[72*a + b + 8*j2] = tA[j2]; ldsB[72*a + b + 8*j2] = tB[j2]; }
  wsync();
  #pragma unroll
  for (int r = 0; r < 8; ++r){ vA[r] = ldsA[72*r + lane]; vB[r] = ldsB[72*r + lane]; }
  #pragma unroll
  for (int r = 1; r < 8; ++r){ vA[r] = cmulc(vA[r], wA[r]); vB[r] = cmulc(vB[r], wA[r]); }
  idft8(vA, tA); idft8(vB, tB);
  #pragma unroll
  for (int j = 0; j < 8; ++j){ vA[j] = tA[j]; vB[j] = tB[j]; }
}

// ---------- p-spectrum precompute: one wave per s ----------
// Writes FFT(p[s]) * (1/512) in the same (lane, reg) layout the conv uses.
__global__ void __launch_bounds__(256)
pfft_kernel(const float* __restrict__ p, float2* __restrict__ pspec){
  __shared__ float2 lds_all[4 * REG_SZ];
  const int lane = threadIdx.x & 63;
  const int wid  = threadIdx.x >> 6;
  float2* lds = lds_all + wid * REG_SZ;
  const int s = blockIdx.x * 4 + wid;

  float2 wA[8], wB[8];
  make_twiddles(lane, wA, wB);

  const float* prow = p + (size_t)s * DIM;
  float2 pf[8];
  #pragma unroll
  for (int j = 0; j < 8; ++j) pf[j] = make_float2(prow[lane + 64*j], 0.f);
  fft512_fwd(pf, lds, lane, wA, wB);
  #pragma unroll
  for (int m = 0; m < 8; ++m){
    pf[m].x *= (1.0f/512.0f); pf[m].y *= (1.0f/512.0f);
    pspec[(size_t)s * DIM + 64*m + lane] = pf[m];
  }
}

// ---------- main kernel ----------
// 128-thread blocks = 2 waves; each wave handles one (s, batch-half):
// 2 iterations x 2 interleaved complex-packed FFT streams (4 rows/iter).
// Grid = SEQ*2/2 = 4096 blocks -> 8192 waves.
// LDS: 2 waves x 2 streams x 656 x 8B = 20992 B -> 7 blocks/CU possible.
__global__ void __launch_bounds__(128, 3)
circconv_kernel(const float* __restrict__ x, const float* __restrict__ p,
                const float2* __restrict__ pspec, float* __restrict__ out){
  __shared__ float2 lds_all[2 * 2 * REG_SZ];
  const int lane = threadIdx.x & 63;
  const int wid  = threadIdx.x >> 6;
  float2* ldsA = lds_all + wid * 2 * REG_SZ;
  float2* ldsB = ldsA + REG_SZ;

  const int g    = blockIdx.x * 2 + wid;   // global wave index
  const int s    = g >> 1;                  // sequence position
  const int half = g & 1;                   // batch half: rows 0-7 or 8-15

  float2 wA[8], wB[8];
  make_twiddles(lane, wA, wB);

  // P spectrum (already scaled by 1/512)
  float2 pf[8];
  if (pspec){
    #pragma unroll
    for (int m = 0; m < 8; ++m) pf[m] = pspec[(size_t)s * DIM + 64*m + lane];
  } else {
    const float* prow = p + (size_t)s * DIM;
    #pragma unroll
    for (int j = 0; j < 8; ++j) pf[j] = make_float2(prow[lane + 64*j], 0.f);
    fft512_fwd(pf, ldsA, lane, wA, wB);
    #pragma unroll
    for (int m = 0; m < 8; ++m){ pf[m].x *= (1.0f/512.0f); pf[m].y *= (1.0f/512.0f); }
  }

  const size_t row_stride = (size_t)SEQ * DIM;
  const int b_lo = half * 8;

  for (int iter = 0; iter < 2; ++iter){
    const int r0 = b_lo + iter * 4;
    const size_t base0 = ((size_t)r0 * SEQ + s) * DIM;
    const size_t base1 = base0 + row_stride;
    const size_t base2 = base0 + 2 * row_stride;
    const size_t base3 = base0 + 3 * row_stride;

    // conv with a real kernel is C-linear: pack row-pairs as re/im
    float2 vA[8], vB[8];
    #pragma unroll
    for (int j = 0; j < 8; ++j){
      vA[j] = make_float2(x[base0 + lane + 64*j], x[base1 + lane + 64*j]);
      vB[j] = make_float2(x[base2 + lane + 64*j], x[base3 + lane + 64*j]);
    }

    fft512_fwd2(vA, vB, ldsA, ldsB, lane, wA, wB);
    #pragma unroll
    for (int m = 0; m < 8; ++m){ vA[m] = cmul(vA[m], pf[m]); vB[m] = cmul(vB[m], pf[m]); }
    fft512_inv2(vA, vB, ldsA, ldsB, lane, wA, wB);

    #pragma unroll
    for (int j = 0; j < 8; ++j){
      out[base0 + lane + 64*j] = vA[j].x;
      out[base1 + lane + 64*j] = vA[j].y;
      out[base2 + lane + 64*j] = vB[j].x;
      out[base3 + lane + 64*j] = vB[j].y;
    }
  }
}

extern "C" void kernel_launch(void* const* d_in, const int* in_sizes, int n_in,
                              void* d_out, int out_size, void* d_ws, size_t ws_size,
                              hipStream_t stream) {
  (void)in_sizes; (void)n_in; (void)out_size;
  const float* x  = (const float*)d_in[0];
  const float* p  = (const float*)d_in[1];
  float* o        = (float*)d_out;

  const size_t pspec_bytes = (size_t)SEQ * DIM * sizeof(float2);  // 16 MiB
  float2* pspec = (ws_size >= pspec_bytes) ? (float2*)d_ws : nullptr;

  if (pspec) pfft_kernel<<<SEQ/4, 256, 0, stream>>>(p, pspec);
  circconv_kernel<<<SEQ*2/2, 128, 0, stream>>>(x, p, pspec, o);
}

// Round 3
// 246.973 us; speedup vs baseline: 1.2528x; 1.2528x over previous
//
#include <hip/hip_runtime.h>
#include <math.h>

#ifndef M_PI
#define M_PI 3.14159265358979323846
#endif

#define SEQ 4096
#define DIM 512

// per-wave LDS region: exchange1 needs <=568 slots, exchange2 <=652; pad to 656
#define REG_SZ 656

// ---------- wave-local LDS sync ----------
// All LDS exchanges are intra-wave (each wave owns a private region). A wave64
// executes in lockstep, so a write->read exchange only needs the DS queue
// drained (lgkmcnt(0)) -- not s_barrier, and no vmcnt drain.
__device__ __forceinline__ void wsync(){
  asm volatile("s_waitcnt lgkmcnt(0)" ::: "memory");
  __builtin_amdgcn_wave_barrier();
}

// ---------- complex helpers (float2 = {re, im}) ----------
__device__ __forceinline__ float2 cadd(float2 a, float2 b){ return make_float2(a.x+b.x, a.y+b.y); }
__device__ __forceinline__ float2 csub(float2 a, float2 b){ return make_float2(a.x-b.x, a.y-b.y); }
__device__ __forceinline__ float2 cmul(float2 a, float2 b){
  return make_float2(fmaf(a.x, b.x, -(a.y*b.y)), fmaf(a.x, b.y, a.y*b.x));
}
__device__ __forceinline__ float2 cmulc(float2 a, float2 b){ // a * conj(b)
  return make_float2(fmaf(a.x, b.x, a.y*b.y), fmaf(a.y, b.x, -(a.x*b.y)));
}
__device__ __forceinline__ float2 mul_mi(float2 a){ return make_float2(a.y, -a.x); } // a * (-i)

// 8-point DFT, natural in / natural out, W = exp(-2*pi*i/8)
__device__ __forceinline__ void dft8(const float2* in, float2* out){
  float2 t0 = cadd(in[0], in[4]), t1 = csub(in[0], in[4]);
  float2 t2 = cadd(in[2], in[6]), t3 = csub(in[2], in[6]);
  float2 E0 = cadd(t0, t2), E2 = csub(t0, t2);
  float2 m3 = mul_mi(t3);
  float2 E1 = cadd(t1, m3), E3 = csub(t1, m3);
  float2 s0 = cadd(in[1], in[5]), s1 = csub(in[1], in[5]);
  float2 s2 = cadd(in[3], in[7]), s3 = csub(in[3], in[7]);
  float2 O0 = cadd(s0, s2), O2 = csub(s0, s2);
  float2 n3 = mul_mi(s3);
  float2 O1 = cadd(s1, n3), O3 = csub(s1, n3);
  const float C = 0.70710678118654752440f;
  float2 w1o = make_float2(C*(O1.x + O1.y), C*(O1.y - O1.x));   // W8^1 * O1
  float2 w2o = mul_mi(O2);                                       // W8^2 * O2
  float2 w3o = make_float2(C*(O3.y - O3.x), -(C*(O3.x + O3.y))); // W8^3 * O3
  out[0] = cadd(E0, O0); out[4] = csub(E0, O0);
  out[1] = cadd(E1, w1o); out[5] = csub(E1, w1o);
  out[2] = cadd(E2, w2o); out[6] = csub(E2, w2o);
  out[3] = cadd(E3, w3o); out[7] = csub(E3, w3o);
}

// unscaled inverse 8-pt DFT: IDFT(a)[k] == DFT(a)[(-k) mod 8]
__device__ __forceinline__ void idft8(const float2* in, float2* out){
  float2 t[8];
  dft8(in, t);
  out[0]=t[0]; out[1]=t[7]; out[2]=t[6]; out[3]=t[5];
  out[4]=t[4]; out[5]=t[3]; out[6]=t[2]; out[7]=t[1];
}

// Twiddles via recurrence: 2 sincosf + 12 cmul (instead of 14 sincosf).
__device__ __forceinline__ void make_twiddles(int lane, float2* wA, float2* wB){
  const int b = lane & 7;
  float sv, cv;
  sincosf(-2.0f*(float)M_PI*(float)lane*(1.0f/512.0f), &sv, &cv);
  const float2 a1 = make_float2(cv, sv);
  sincosf(-2.0f*(float)M_PI*(float)b*(1.0f/64.0f), &sv, &cv);
  const float2 b1 = make_float2(cv, sv);
  wA[0] = make_float2(1.f, 0.f); wB[0] = make_float2(1.f, 0.f);
  wA[1] = a1; wB[1] = b1;
  #pragma unroll
  for (int r = 2; r < 8; ++r){ wA[r] = cmul(wA[r-1], a1); wB[r] = cmul(wB[r-1], b1); }
}

// ---------- 512-pt FFT, one wave (64 lanes x 8 complex regs) ----------
// Exchange addressing (bank-pair = (idx mod 16) must be bijective over each
// aligned 16-lane phase for conflict-free 8B LDS access):
//   exchange1: write idx = 72*r + lane        -> pair (8r+lane)%16  bijective
//              read  idx = 72*a + b + 8*j2    -> pair (8a+b)%16     bijective
//   exchange2: f2(a,u,w) = a + 82*u + 10*w    (bijective: a+10w<=77<82)
//              write (u const): pair (a+10w)%16  -> {0,10,4,14,8,2,12,6}+bit  OK
//              read  (w const): pair (a+2u)%16   -> bijective                 OK
__device__ __forceinline__ void fft512_fwd(float2* v, float2* lds, int lane,
                                           const float2* wA, const float2* wB){
  const int a = lane >> 3, b = lane & 7;
  float2 t[8];
  dft8(v, t);
  #pragma unroll
  for (int r = 1; r < 8; ++r) t[r] = cmul(t[r], wA[r]);
  wsync();
  #pragma unroll
  for (int r = 0; r < 8; ++r) lds[72*r + lane] = t[r];
  wsync();
  #pragma unroll
  for (int j2 = 0; j2 < 8; ++j2) v[j2] = lds[72*a + b + 8*j2];
  dft8(v, t);
  #pragma unroll
  for (int r2 = 1; r2 < 8; ++r2) t[r2] = cmul(t[r2], wB[r2]);
  wsync();
  #pragma unroll
  for (int r2 = 0; r2 < 8; ++r2) lds[a + 82*r2 + 10*b] = t[r2];
  wsync();
  #pragma unroll
  for (int i2 = 0; i2 < 8; ++i2) v[i2] = lds[a + 82*b + 10*i2];
  dft8(v, t);
  #pragma unroll
  for (int m = 0; m < 8; ++m) v[m] = t[m];
}

// Inverse (DIT): consumes digit-reversed layout, produces natural order,
// scaled by 512 (1/512 folded into the p-spectrum).
__device__ __forceinline__ void fft512_inv(float2* v, float2* lds, int lane,
                                           const float2* wA, const float2* wB){
  const int a = lane >> 3, b = lane & 7;
  float2 t[8];
  idft8(v, t);
  wsync();
  #pragma unroll
  for (int i2 = 0; i2 < 8; ++i2) lds[a + 82*b + 10*i2] = t[i2];
  wsync();
  #pragma unroll
  for (int r2 = 0; r2 < 8; ++r2) v[r2] = lds[a + 82*r2 + 10*b];
  #pragma unroll
  for (int r2 = 1; r2 < 8; ++r2) v[r2] = cmulc(v[r2], wB[r2]);
  idft8(v, t);
  wsync();
  #pragma unroll
  for (int j2 = 0; j2 < 8; ++j2) lds[72*a + b + 8*j2] = t[j2];
  wsync();
  #pragma unroll
  for (int r = 0; r < 8; ++r) v[r] = lds[72*r + lane];
  #pragma unroll
  for (int r = 1; r < 8; ++r) v[r] = cmulc(v[r], wA[r]);
  idft8(v, t);
  #pragma unroll
  for (int j = 0; j < 8; ++j) v[j] = t[j];
}

// ---------- p-spectrum precompute: one wave per s ----------
// Writes FFT(p[s]) * (1/512) in the same (lane, reg) layout the conv uses.
__global__ void __launch_bounds__(256)
pfft_kernel(const float* __restrict__ p, float2* __restrict__ pspec){
  __shared__ float2 lds_all[4 * REG_SZ];
  const int lane = threadIdx.x & 63;
  const int wid  = threadIdx.x >> 6;
  float2* lds = lds_all + wid * REG_SZ;
  const int s = blockIdx.x * 4 + wid;

  float2 wA[8], wB[8];
  make_twiddles(lane, wA, wB);

  const float* prow = p + (size_t)s * DIM;
  float2 pf[8];
  #pragma unroll
  for (int j = 0; j < 8; ++j) pf[j] = make_float2(prow[lane + 64*j], 0.f);
  fft512_fwd(pf, lds, lane, wA, wB);
  #pragma unroll
  for (int m = 0; m < 8; ++m){
    pf[m].x *= (1.0f/512.0f); pf[m].y *= (1.0f/512.0f);
    pspec[(size_t)s * DIM + 64*m + lane] = pf[m];
  }
}

// ---------- main kernel: one wave per (s, row-pair) ----------
// 4096 s x 8 pairs = 32768 waves (4x round-0's TLP), 8192 blocks x 256 thr.
// Each wave: load pspec row + 2 x-rows, 1 fwd + 1 inv FFT, store 2 rows.
// Single-stream FFT keeps VGPR ~90 (no spill); LDS 21 KB/block -> 7 blocks/CU
// possible, VGPR -> 5-6 waves/SIMD; either way far above round-0's ~2/SIMD.
__global__ void __launch_bounds__(256)
circconv_kernel(const float* __restrict__ x, const float2* __restrict__ pspec,
                float* __restrict__ out){
  __shared__ float2 lds_all[4 * REG_SZ];
  const int lane = threadIdx.x & 63;
  const int wid  = threadIdx.x >> 6;
  float2* lds = lds_all + wid * REG_SZ;

  const int g    = blockIdx.x * 4 + wid;   // global wave index
  const int s    = g >> 3;                  // sequence position
  const int pr   = g & 7;                   // row-pair: rows 2pr, 2pr+1

  const size_t row_stride = (size_t)SEQ * DIM;
  const size_t base0 = ((size_t)(2*pr) * SEQ + s) * DIM;
  const size_t base1 = base0 + row_stride;

  // issue all global loads first; twiddle computation hides part of the
  // latency, TLP (20+ waves/CU) hides the rest
  float2 pf[8];
  #pragma unroll
  for (int m = 0; m < 8; ++m) pf[m] = pspec[(size_t)s * DIM + 64*m + lane];

  float re[8], im[8];
  #pragma unroll
  for (int j = 0; j < 8; ++j){
    re[j] = x[base0 + lane + 64*j];
    im[j] = x[base1 + lane + 64*j];
  }

  float2 wA[8], wB[8];
  make_twiddles(lane, wA, wB);

  // conv with a real kernel is C-linear: pack rows (2pr, 2pr+1) as re/im
  float2 v[8];
  #pragma unroll
  for (int j = 0; j < 8; ++j) v[j] = make_float2(re[j], im[j]);

  fft512_fwd(v, lds, lane, wA, wB);
  #pragma unroll
  for (int m = 0; m < 8; ++m) v[m] = cmul(v[m], pf[m]);
  fft512_inv(v, lds, lane, wA, wB);

  #pragma unroll
  for (int j = 0; j < 8; ++j){
    out[base0 + lane + 64*j] = v[j].x;
    out[base1 + lane + 64*j] = v[j].y;
  }
}

// ---------- fallback (no workspace): in-wave p-FFT, round-0 structure ----------
__global__ void __launch_bounds__(256)
circconv_fallback_kernel(const float* __restrict__ x, const float* __restrict__ p,
                         float* __restrict__ out){
  __shared__ float2 lds_all[4 * REG_SZ];
  const int lane = threadIdx.x & 63;
  const int wid  = threadIdx.x >> 6;
  float2* lds = lds_all + wid * REG_SZ;

  const int g    = blockIdx.x * 4 + wid;
  const int s    = g >> 1;
  const int half = g & 1;

  float2 wA[8], wB[8];
  make_twiddles(lane, wA, wB);

  float2 pf[8];
  {
    const float* prow = p + (size_t)s * DIM;
    #pragma unroll
    for (int j = 0; j < 8; ++j) pf[j] = make_float2(prow[lane + 64*j], 0.f);
    fft512_fwd(pf, lds, lane, wA, wB);
    #pragma unroll
    for (int m = 0; m < 8; ++m){ pf[m].x *= (1.0f/512.0f); pf[m].y *= (1.0f/512.0f); }
  }

  const size_t row_stride = (size_t)SEQ * DIM;
  const int b_lo = half * 8;
  for (int bb = b_lo; bb < b_lo + 8; bb += 2){
    const size_t base0 = ((size_t)bb * SEQ + s) * DIM;
    const size_t base1 = base0 + row_stride;
    float2 v[8];
    #pragma unroll
    for (int j = 0; j < 8; ++j)
      v[j] = make_float2(x[base0 + lane + 64*j], x[base1 + lane + 64*j]);
    fft512_fwd(v, lds, lane, wA, wB);
    #pragma unroll
    for (int m = 0; m < 8; ++m) v[m] = cmul(v[m], pf[m]);
    fft512_inv(v, lds, lane, wA, wB);
    #pragma unroll
    for (int j = 0; j < 8; ++j){
      out[base0 + lane + 64*j] = v[j].x;
      out[base1 + lane + 64*j] = v[j].y;
    }
  }
}

extern "C" void kernel_launch(void* const* d_in, const int* in_sizes, int n_in,
                              void* d_out, int out_size, void* d_ws, size_t ws_size,
                              hipStream_t stream) {
  (void)in_sizes; (void)n_in; (void)out_size;
  const float* x  = (const float*)d_in[0];
  const float* p  = (const float*)d_in[1];
  float* o        = (float*)d_out;

  const size_t pspec_bytes = (size_t)SEQ * DIM * sizeof(float2);  // 16 MiB
  if (ws_size >= pspec_bytes){
    float2* pspec = (float2*)d_ws;
    pfft_kernel<<<SEQ/4, 256, 0, stream>>>(p, pspec);
    circconv_kernel<<<SEQ*8/4, 256, 0, stream>>>(x, pspec, o);
  } else {
    circconv_fallback_kernel<<<SEQ*2/4, 256, 0, stream>>>(x, p, o);
  }
}